// Round 1
// baseline (1187.832 us; speedup 1.0000x reference)
//
#include <hip/hip_runtime.h>
#include <hip/hip_bf16.h>
#include <math.h>

// DeepSeekMoE: T=4096 tokens, H=1024, F=4096, E=8, top-2 sigmoid routing.
// Strategy: bf16 MFMA GEMMs (m97 128^2-tile structure, global_load_lds),
// expert-bucketed gather for routed FFN (only 2T rows of work, not E*T).

#define T_TOK 4096
#define H_DIM 1024
#define F_DIM 4096
#define NEXP  8
#define RT    (2 * T_TOK)   // total routed rows (always exactly 2T)
#define RPAD  128           // padding rows for tile-tail reads

typedef __bf16 bf16_t;
typedef __bf16 bf16x8 __attribute__((ext_vector_type(8)));
typedef float  f32x4  __attribute__((ext_vector_type(4)));
typedef unsigned short u16x8 __attribute__((ext_vector_type(8)));

__device__ __forceinline__ unsigned short f2bf(float f) {
  union { bf16_t b; unsigned short u; } cv;
  cv.b = (bf16_t)f;   // fptrunc float->bfloat is RNE
  return cv.u;
}

__device__ __forceinline__ float gelu_exact(float v) {
  return 0.5f * v * (1.0f + erff(v * 0.70710678118654752f));
}

// ---------------------------------------------------------------- small kernels

__global__ void zero_kernel(int* p) {
  if (threadIdx.x < 16) p[threadIdx.x] = 0;   // counts[8] + cursor[8]
}

__global__ void convert_kernel(const float* __restrict__ src,
                               unsigned short* __restrict__ dst, int n8) {
  int i = blockIdx.x * blockDim.x + threadIdx.x;
  int stride = gridDim.x * blockDim.x;
  for (; i < n8; i += stride) {
    const f32x4* s = (const f32x4*)src + (long)i * 2;
    f32x4 v0 = s[0], v1 = s[1];
    u16x8 o;
    #pragma unroll
    for (int j = 0; j < 4; ++j) { o[j] = f2bf(v0[j]); o[4 + j] = f2bf(v1[j]); }
    *(u16x8*)(dst + (long)i * 8) = o;
  }
}

// one wave per token: 8 gate scores -> sigmoid -> top2
__global__ void gate_kernel(const float* __restrict__ x, const float* __restrict__ gw,
                            const float* __restrict__ gb, const float* __restrict__ rb,
                            int* __restrict__ tok_e, float* __restrict__ tok_w,
                            int* __restrict__ counts) {
  int tkn = blockIdx.x;
  int lane = threadIdx.x;
  float acc[NEXP];
  #pragma unroll
  for (int e = 0; e < NEXP; ++e) acc[e] = 0.f;
  const float* xr = x + (long)tkn * H_DIM;
  for (int k = lane; k < H_DIM; k += 64) {
    float xv = xr[k];
    #pragma unroll
    for (int e = 0; e < NEXP; ++e) acc[e] += xv * gw[e * H_DIM + k];
  }
  #pragma unroll
  for (int off = 32; off > 0; off >>= 1) {
    #pragma unroll
    for (int e = 0; e < NEXP; ++e) acc[e] += __shfl_xor(acc[e], off, 64);
  }
  if (lane == 0) {
    float s[NEXP];
    #pragma unroll
    for (int e = 0; e < NEXP; ++e)
      s[e] = 1.f / (1.f + expf(-(acc[e] + gb[e] + rb[e])));
    int e0 = 0;
    #pragma unroll
    for (int e = 1; e < NEXP; ++e) if (s[e] > s[e0]) e0 = e;     // first-occurrence ties
    int e1 = (e0 == 0) ? 1 : 0;
    #pragma unroll
    for (int e = 0; e < NEXP; ++e) if (e != e0 && e != e1 && s[e] > s[e1]) e1 = e;
    tok_e[2 * tkn] = e0;  tok_e[2 * tkn + 1] = e1;
    tok_w[2 * tkn] = s[e0]; tok_w[2 * tkn + 1] = s[e1];
    atomicAdd(&counts[e0], 1);
    atomicAdd(&counts[e1], 1);
  }
}

__global__ void scan_kernel(const int* __restrict__ counts, int* __restrict__ offs) {
  if (threadIdx.x == 0) {
    int o = 0;
    for (int e = 0; e < NEXP; ++e) { offs[e] = o; o += counts[e]; }
  }
}

__global__ void build_kernel(const int* __restrict__ tok_e, const float* __restrict__ tok_w,
                             const int* __restrict__ offs, int* __restrict__ cursor,
                             int* __restrict__ btok, float* __restrict__ bw,
                             int* __restrict__ tokpos) {
  int tkn = blockIdx.x * blockDim.x + threadIdx.x;
  if (tkn >= T_TOK) return;
  #pragma unroll
  for (int k = 0; k < 2; ++k) {
    int e = tok_e[2 * tkn + k];
    int p = offs[e] + atomicAdd(&cursor[e], 1);
    btok[p] = tkn;
    bw[p] = tok_w[2 * tkn + k];
    tokpos[2 * tkn + k] = p;
  }
}

// copy x row (fp32) -> gathered bf16 row, bucket order
__global__ void gather_kernel(const float* __restrict__ x, const int* __restrict__ btok,
                              unsigned short* __restrict__ gx) {
  int p = blockIdx.x, tid = threadIdx.x;  // 128 threads * 8 elems
  int tkn = btok[p];
  const f32x4* s = (const f32x4*)(x + (long)tkn * H_DIM);
  f32x4 v0 = s[tid * 2], v1 = s[tid * 2 + 1];
  u16x8 o;
  #pragma unroll
  for (int j = 0; j < 4; ++j) { o[j] = f2bf(v0[j]); o[4 + j] = f2bf(v1[j]); }
  *(u16x8*)(gx + (long)p * H_DIM + tid * 8) = o;
}

__global__ void combine_kernel(float* __restrict__ out, const float* __restrict__ rout,
                               const int* __restrict__ tokpos) {
  int tkn = blockIdx.x, c = threadIdx.x;  // 256 threads * float4
  int p0 = tokpos[2 * tkn], p1 = tokpos[2 * tkn + 1];
  f32x4* o = (f32x4*)out + (long)tkn * 256;
  const f32x4* a = (const f32x4*)rout + (long)p0 * 256;
  const f32x4* b = (const f32x4*)rout + (long)p1 * 256;
  o[c] = o[c] + a[c] + b[c];
}

// ---------------------------------------------------------------- GEMM (NT, bf16 MFMA)
// C[M,N] = A[M,K] @ B[N,K]^T ; m97 structure: 128x128 tile, BK=32, 4 waves,
// global_load_lds width-16, 1 barrier per K-step, 16x16x32 bf16 MFMA.
// MODE 0: +bias, exact GELU, bf16 out. MODE 1: +bias, f32 out.
// MODE 2: (+bias)*rowscale, f32 out.
template<int MODE, bool ROUTED>
__global__ __launch_bounds__(256)
void gemm_nt(const unsigned short* __restrict__ A, const unsigned short* __restrict__ B,
             const float* __restrict__ bias, void* __restrict__ Cv,
             int N, int K,
             const int* __restrict__ cnts, const int* __restrict__ offs,
             const float* __restrict__ rowscale,
             long strideBe, int strideBiasE) {
  __shared__ __align__(16) unsigned short lds[2][2][128][32];
  const int mb = blockIdx.x, nb = blockIdx.y;
  int mcnt = 1 << 30;
  const float* rs = rowscale;
  if (ROUTED) {
    const int e = blockIdx.z;
    mcnt = cnts[e];
    if (mb * 128 >= mcnt) return;
    const long off = offs[e];
    A += off * (long)K;
    B += (long)e * strideBe;
    bias += (long)e * strideBiasE;
    if (MODE == 0) Cv = (void*)((unsigned short*)Cv + off * (long)N);
    else           Cv = (void*)((float*)Cv + off * (long)N);
    if (MODE == 2) rs = rowscale + off;
  }
  const int t = threadIdx.x;
  f32x4 acc[4][4] = {};
  const int nk = K >> 5;

  auto stage = [&](int kt, int buf) {
    #pragma unroll
    for (int i = 0; i < 2; ++i) {
      const int row = i * 64 + (t >> 2);
      const int ch = (t & 3) * 8;
      const unsigned short* ga = A + (long)(mb * 128 + row) * K + kt * 32 + ch;
      const unsigned short* gb = B + (long)(nb * 128 + row) * K + kt * 32 + ch;
      unsigned short* la = &lds[buf][0][0][0] + i * 2048 + t * 8;
      unsigned short* lb = &lds[buf][1][0][0] + i * 2048 + t * 8;
      __builtin_amdgcn_global_load_lds((const __attribute__((address_space(1))) unsigned int*)ga,
                                       (__attribute__((address_space(3))) unsigned int*)la, 16, 0, 0);
      __builtin_amdgcn_global_load_lds((const __attribute__((address_space(1))) unsigned int*)gb,
                                       (__attribute__((address_space(3))) unsigned int*)lb, 16, 0, 0);
    }
  };

  const int l = t & 63;
  const int w = t >> 6;
  const int wr = (w >> 1) * 64, wc = (w & 1) * 64;
  const int lr = l & 15, lk = (l >> 4) * 8;

  auto compute = [&](int buf) {
    bf16x8 a[4], b[4];
    #pragma unroll
    for (int m = 0; m < 4; ++m) a[m] = *(const bf16x8*)&lds[buf][0][wr + m * 16 + lr][lk];
    #pragma unroll
    for (int n = 0; n < 4; ++n) b[n] = *(const bf16x8*)&lds[buf][1][wc + n * 16 + lr][lk];
    #pragma unroll
    for (int m = 0; m < 4; ++m)
      #pragma unroll
      for (int n = 0; n < 4; ++n)
        acc[m][n] = __builtin_amdgcn_mfma_f32_16x16x32_bf16(a[m], b[n], acc[m][n], 0, 0, 0);
  };

  stage(0, 0);
  asm volatile("s_waitcnt vmcnt(0)" ::: "memory");
  __syncthreads();
  for (int kt = 0; kt < nk - 1; ++kt) {
    const int cur = kt & 1;
    stage(kt + 1, cur ^ 1);
    compute(cur);
    asm volatile("s_waitcnt vmcnt(0)" ::: "memory");
    __syncthreads();
  }
  compute((nk - 1) & 1);

  // epilogue: C/D layout col=lane&15, row=(lane>>4)*4+j (m89-verified)
  #pragma unroll
  for (int m = 0; m < 4; ++m) {
    #pragma unroll
    for (int n = 0; n < 4; ++n) {
      const int col = nb * 128 + wc + n * 16 + lr;
      const float bc = bias[col];
      #pragma unroll
      for (int j = 0; j < 4; ++j) {
        const int lrow = mb * 128 + wr + m * 16 + (l >> 4) * 4 + j;
        if (ROUTED && lrow >= mcnt) continue;
        float v = acc[m][n][j] + bc;
        if (MODE == 0) {
          ((unsigned short*)Cv)[(long)lrow * N + col] = f2bf(gelu_exact(v));
        } else if (MODE == 1) {
          ((float*)Cv)[(long)lrow * N + col] = v;
        } else {
          ((float*)Cv)[(long)lrow * N + col] = v * rs[lrow];
        }
      }
    }
  }
}

// ---------------------------------------------------------------- host

extern "C" void kernel_launch(void* const* d_in, const int* in_sizes, int n_in,
                              void* d_out, int out_size, void* d_ws, size_t ws_size,
                              hipStream_t stream) {
  const float* x   = (const float*)d_in[0];
  const float* gw  = (const float*)d_in[1];
  const float* gb  = (const float*)d_in[2];
  const float* rb  = (const float*)d_in[3];
  const float* sw1 = (const float*)d_in[4];
  const float* sb1 = (const float*)d_in[5];
  const float* sw2 = (const float*)d_in[6];
  const float* sb2 = (const float*)d_in[7];
  const float* ew1 = (const float*)d_in[8];
  const float* eb1 = (const float*)d_in[9];
  const float* ew2 = (const float*)d_in[10];
  const float* eb2 = (const float*)d_in[11];

  // workspace layout (~280 MB)
  char* wsp = (char*)d_ws;
  size_t o = 0;
  auto alloc = [&](size_t b) -> void* {
    void* p = wsp + o;
    o = (o + b + 255) & ~(size_t)255;
    return p;
  };
  unsigned short* x_bf = (unsigned short*)alloc((size_t)T_TOK * H_DIM * 2);
  unsigned short* w1s  = (unsigned short*)alloc((size_t)F_DIM * H_DIM * 2);
  unsigned short* w2s  = (unsigned short*)alloc((size_t)H_DIM * F_DIM * 2);
  unsigned short* w1e  = (unsigned short*)alloc((size_t)NEXP * F_DIM * H_DIM * 2);
  unsigned short* w2e  = (unsigned short*)alloc((size_t)NEXP * H_DIM * F_DIM * 2);
  unsigned short* gx   = (unsigned short*)alloc((size_t)(RT + RPAD) * H_DIM * 2);
  unsigned short* hbuf = (unsigned short*)alloc((size_t)(RT + RPAD) * F_DIM * 2); // shared h uses rows [0,T)
  float* rout          = (float*)alloc((size_t)RT * H_DIM * 4);
  int*   tok_e  = (int*)alloc(2 * T_TOK * 4);
  float* tok_w  = (float*)alloc(2 * T_TOK * 4);
  int*   tokpos = (int*)alloc(2 * T_TOK * 4);
  int*   btok   = (int*)alloc(RT * 4);
  float* bw     = (float*)alloc(RT * 4);
  int*   meta   = (int*)alloc(1024);   // counts[8], cursor[8], offs[8]
  int* counts = meta, *cursor = meta + 8, *offs = meta + 16;
  (void)ws_size; (void)in_sizes; (void)n_in; (void)out_size;

  float* out = (float*)d_out;

  zero_kernel<<<1, 64, 0, stream>>>(meta);
  convert_kernel<<<2048, 256, 0, stream>>>(x,   x_bf, T_TOK * H_DIM / 8);
  convert_kernel<<<2048, 256, 0, stream>>>(sw1, w1s, F_DIM * H_DIM / 8);
  convert_kernel<<<2048, 256, 0, stream>>>(sw2, w2s, H_DIM * F_DIM / 8);
  convert_kernel<<<2048, 256, 0, stream>>>(ew1, w1e, NEXP * F_DIM * H_DIM / 8);
  convert_kernel<<<2048, 256, 0, stream>>>(ew2, w2e, NEXP * H_DIM * F_DIM / 8);
  gate_kernel<<<T_TOK, 64, 0, stream>>>(x, gw, gb, rb, tok_e, tok_w, counts);
  scan_kernel<<<1, 1, 0, stream>>>(counts, offs);
  build_kernel<<<T_TOK / 256, 256, 0, stream>>>(tok_e, tok_w, offs, cursor, btok, bw, tokpos);
  gather_kernel<<<RT, 128, 0, stream>>>(x, btok, gx);

  // shared FFN: h = gelu(x@W1^T + b1); out = h@W2^T + b2
  gemm_nt<0, false><<<dim3(T_TOK / 128, F_DIM / 128), 256, 0, stream>>>(
      x_bf, w1s, sb1, hbuf, F_DIM, H_DIM, nullptr, nullptr, nullptr, 0, 0);
  gemm_nt<1, false><<<dim3(T_TOK / 128, H_DIM / 128), 256, 0, stream>>>(
      hbuf, w2s, sb2, out, H_DIM, F_DIM, nullptr, nullptr, nullptr, 0, 0);

  // routed FFN (expert-bucketed rows; grid.z = expert, early-exit past cnt)
  gemm_nt<0, true><<<dim3(T_TOK / 128, F_DIM / 128, NEXP), 256, 0, stream>>>(
      gx, w1e, eb1, hbuf, F_DIM, H_DIM, counts, offs, nullptr,
      (long)F_DIM * H_DIM, F_DIM);
  gemm_nt<2, true><<<dim3(T_TOK / 128, H_DIM / 128, NEXP), 256, 0, stream>>>(
      hbuf, w2e, eb2, rout, H_DIM, F_DIM, counts, offs, bw,
      (long)H_DIM * F_DIM, H_DIM);

  combine_kernel<<<T_TOK, 256, 0, stream>>>(out, rout, tokpos);
}

// Round 2
// 776.026 us; speedup vs baseline: 1.5307x; 1.5307x over previous
//
#include <hip/hip_runtime.h>
#include <hip/hip_bf16.h>
#include <math.h>

// DeepSeekMoE: T=4096 tokens, H=1024, F=4096, E=8, top-2 sigmoid routing.
// Round 2: GEMM1s (K=1024) -> 256x256/BK=32/8-wave 2-phase (m248: ~655 TF for
// grouped 256^2 K=1024); T1 bijective XCD swizzle on all GEMMs.
// Separate hbuf regions: shared h rows [0,T), routed h rows in own buffer.

#define T_TOK 4096
#define H_DIM 1024
#define F_DIM 4096
#define NEXP  8
#define RT    (2 * T_TOK)   // total routed rows (always exactly 2T)
#define RPAD  512           // padding rows for 256-tile tail reads

typedef __bf16 bf16_t;
typedef __bf16 bf16x8 __attribute__((ext_vector_type(8)));
typedef float  f32x4  __attribute__((ext_vector_type(4)));
typedef unsigned short u16x8 __attribute__((ext_vector_type(8)));

__device__ __forceinline__ unsigned short f2bf(float f) {
  union { bf16_t b; unsigned short u; } cv;
  cv.b = (bf16_t)f;   // fptrunc float->bfloat is RNE
  return cv.u;
}

__device__ __forceinline__ float gelu_exact(float v) {
  return 0.5f * v * (1.0f + erff(v * 0.70710678118654752f));
}

// bijective XCD swizzle (m204): contiguous wg chunk per XCD
__device__ __forceinline__ int xcd_swizzle(int orig, int nwg) {
  const int q = nwg >> 3, r = nwg & 7;
  const int xcd = orig & 7, idx = orig >> 3;
  return (xcd < r ? xcd * (q + 1) : r * (q + 1) + (xcd - r) * q) + idx;
}

// ---------------------------------------------------------------- small kernels

__global__ void zero_kernel(int* p) {
  if (threadIdx.x < 16) p[threadIdx.x] = 0;   // counts[8] + cursor[8]
}

__global__ void convert_kernel(const float* __restrict__ src,
                               unsigned short* __restrict__ dst, int n8) {
  int i = blockIdx.x * blockDim.x + threadIdx.x;
  int stride = gridDim.x * blockDim.x;
  for (; i < n8; i += stride) {
    const f32x4* s = (const f32x4*)src + (long)i * 2;
    f32x4 v0 = s[0], v1 = s[1];
    u16x8 o;
    #pragma unroll
    for (int j = 0; j < 4; ++j) { o[j] = f2bf(v0[j]); o[4 + j] = f2bf(v1[j]); }
    *(u16x8*)(dst + (long)i * 8) = o;
  }
}

// one wave per token: 8 gate scores -> sigmoid -> top2
__global__ void gate_kernel(const float* __restrict__ x, const float* __restrict__ gw,
                            const float* __restrict__ gb, const float* __restrict__ rb,
                            int* __restrict__ tok_e, float* __restrict__ tok_w,
                            int* __restrict__ counts) {
  int tkn = blockIdx.x;
  int lane = threadIdx.x;
  float acc[NEXP];
  #pragma unroll
  for (int e = 0; e < NEXP; ++e) acc[e] = 0.f;
  const float* xr = x + (long)tkn * H_DIM;
  for (int k = lane; k < H_DIM; k += 64) {
    float xv = xr[k];
    #pragma unroll
    for (int e = 0; e < NEXP; ++e) acc[e] += xv * gw[e * H_DIM + k];
  }
  #pragma unroll
  for (int off = 32; off > 0; off >>= 1) {
    #pragma unroll
    for (int e = 0; e < NEXP; ++e) acc[e] += __shfl_xor(acc[e], off, 64);
  }
  if (lane == 0) {
    float s[NEXP];
    #pragma unroll
    for (int e = 0; e < NEXP; ++e)
      s[e] = 1.f / (1.f + expf(-(acc[e] + gb[e] + rb[e])));
    int e0 = 0;
    #pragma unroll
    for (int e = 1; e < NEXP; ++e) if (s[e] > s[e0]) e0 = e;     // first-occurrence ties
    int e1 = (e0 == 0) ? 1 : 0;
    #pragma unroll
    for (int e = 0; e < NEXP; ++e) if (e != e0 && e != e1 && s[e] > s[e1]) e1 = e;
    tok_e[2 * tkn] = e0;  tok_e[2 * tkn + 1] = e1;
    tok_w[2 * tkn] = s[e0]; tok_w[2 * tkn + 1] = s[e1];
    atomicAdd(&counts[e0], 1);
    atomicAdd(&counts[e1], 1);
  }
}

__global__ void scan_kernel(const int* __restrict__ counts, int* __restrict__ offs) {
  if (threadIdx.x == 0) {
    int o = 0;
    for (int e = 0; e < NEXP; ++e) { offs[e] = o; o += counts[e]; }
  }
}

__global__ void build_kernel(const int* __restrict__ tok_e, const float* __restrict__ tok_w,
                             const int* __restrict__ offs, int* __restrict__ cursor,
                             int* __restrict__ btok, float* __restrict__ bw,
                             int* __restrict__ tokpos) {
  int tkn = blockIdx.x * blockDim.x + threadIdx.x;
  if (tkn >= T_TOK) return;
  #pragma unroll
  for (int k = 0; k < 2; ++k) {
    int e = tok_e[2 * tkn + k];
    int p = offs[e] + atomicAdd(&cursor[e], 1);
    btok[p] = tkn;
    bw[p] = tok_w[2 * tkn + k];
    tokpos[2 * tkn + k] = p;
  }
}

// copy x row (fp32) -> gathered bf16 row, bucket order
__global__ void gather_kernel(const float* __restrict__ x, const int* __restrict__ btok,
                              unsigned short* __restrict__ gx) {
  int p = blockIdx.x, tid = threadIdx.x;  // 128 threads * 8 elems
  int tkn = btok[p];
  const f32x4* s = (const f32x4*)(x + (long)tkn * H_DIM);
  f32x4 v0 = s[tid * 2], v1 = s[tid * 2 + 1];
  u16x8 o;
  #pragma unroll
  for (int j = 0; j < 4; ++j) { o[j] = f2bf(v0[j]); o[4 + j] = f2bf(v1[j]); }
  *(u16x8*)(gx + (long)p * H_DIM + tid * 8) = o;
}

__global__ void combine_kernel(float* __restrict__ out, const float* __restrict__ rout,
                               const int* __restrict__ tokpos) {
  int tkn = blockIdx.x, c = threadIdx.x;  // 256 threads * float4
  int p0 = tokpos[2 * tkn], p1 = tokpos[2 * tkn + 1];
  f32x4* o = (f32x4*)out + (long)tkn * 256;
  const f32x4* a = (const f32x4*)rout + (long)p0 * 256;
  const f32x4* b = (const f32x4*)rout + (long)p1 * 256;
  o[c] = o[c] + a[c] + b[c];
}

// ---------------------------------------------------------------- 256^2 GEMM (NT, bf16)
// C[M,N] = A[M,K] @ B[N,K]^T ; 256x256 tile, BK=32, 8 waves (2Mx4N),
// double-buffered LDS (64 KB), global_load_lds width-16, 2-phase schedule.
// Epilogue: +bias, exact GELU, bf16 out (GEMM1 only).
template<bool ROUTED>
__global__ __launch_bounds__(512)
void gemm256(const unsigned short* __restrict__ A, const unsigned short* __restrict__ B,
             const float* __restrict__ bias, unsigned short* __restrict__ C,
             int N, int K,
             const int* __restrict__ cnts, const int* __restrict__ offs,
             long strideBe, int strideBiasE) {
  __shared__ __align__(16) unsigned short lds[2][2][256][32];   // 64 KB
  const int gxd = gridDim.x;
  const int nwg = gxd * gridDim.y;
  const int wg = xcd_swizzle(blockIdx.y * gxd + blockIdx.x, nwg);
  const int mb = wg % gxd, nb = wg / gxd;

  int mcnt = 1 << 30;
  if (ROUTED) {
    const int e = blockIdx.z;
    mcnt = cnts[e];
    if (mb * 256 >= mcnt) return;
    const long off = offs[e];
    A += off * (long)K;
    B += (long)e * strideBe;
    bias += (long)e * strideBiasE;
    C += off * (long)N;
  }
  const int t = threadIdx.x;
  f32x4 acc[8][4] = {};
  const int nk = K >> 5;

  auto stage = [&](int kt, int buf) {
    #pragma unroll
    for (int i = 0; i < 2; ++i) {
      const int row = i * 128 + (t >> 2);
      const int ch = (t & 3) * 8;
      const unsigned short* ga = A + (long)(mb * 256 + row) * K + kt * 32 + ch;
      const unsigned short* gb = B + (long)(nb * 256 + row) * K + kt * 32 + ch;
      unsigned short* la = &lds[buf][0][0][0] + i * 4096 + t * 8;
      unsigned short* lb = &lds[buf][1][0][0] + i * 4096 + t * 8;
      __builtin_amdgcn_global_load_lds((const __attribute__((address_space(1))) unsigned int*)ga,
                                       (__attribute__((address_space(3))) unsigned int*)la, 16, 0, 0);
      __builtin_amdgcn_global_load_lds((const __attribute__((address_space(1))) unsigned int*)gb,
                                       (__attribute__((address_space(3))) unsigned int*)lb, 16, 0, 0);
    }
  };

  const int l = t & 63;
  const int w = t >> 6;                       // 8 waves: 2M x 4N
  const int wr = (w >> 2) * 128, wc = (w & 3) * 64;
  const int lr = l & 15, lk = (l >> 4) * 8;

  auto compute = [&](int buf) {
    bf16x8 a[8], b[4];
    #pragma unroll
    for (int m = 0; m < 8; ++m) a[m] = *(const bf16x8*)&lds[buf][0][wr + m * 16 + lr][lk];
    #pragma unroll
    for (int n = 0; n < 4; ++n) b[n] = *(const bf16x8*)&lds[buf][1][wc + n * 16 + lr][lk];
    #pragma unroll
    for (int m = 0; m < 8; ++m)
      #pragma unroll
      for (int n = 0; n < 4; ++n)
        acc[m][n] = __builtin_amdgcn_mfma_f32_16x16x32_bf16(a[m], b[n], acc[m][n], 0, 0, 0);
  };

  stage(0, 0);
  asm volatile("s_waitcnt vmcnt(0)" ::: "memory");
  __syncthreads();
  for (int kt = 0; kt < nk - 1; ++kt) {
    const int cur = kt & 1;
    stage(kt + 1, cur ^ 1);
    compute(cur);
    asm volatile("s_waitcnt vmcnt(0)" ::: "memory");
    __syncthreads();
  }
  compute((nk - 1) & 1);

  // epilogue: C/D layout col=lane&15, row=(lane>>4)*4+j (m89-verified)
  #pragma unroll
  for (int m = 0; m < 8; ++m) {
    #pragma unroll
    for (int n = 0; n < 4; ++n) {
      const int col = nb * 256 + wc + n * 16 + lr;
      const float bc = bias[col];
      #pragma unroll
      for (int j = 0; j < 4; ++j) {
        const int lrow = mb * 256 + wr + m * 16 + (l >> 4) * 4 + j;
        if (ROUTED && lrow >= mcnt) continue;
        float v = acc[m][n][j] + bc;
        C[(long)lrow * N + col] = f2bf(gelu_exact(v));
      }
    }
  }
}

// ---------------------------------------------------------------- 128^2 GEMM (GEMM2s)
// MODE 1: +bias, f32 out. MODE 2: (+bias)*rowscale, f32 out.
template<int MODE, bool ROUTED>
__global__ __launch_bounds__(256)
void gemm_nt(const unsigned short* __restrict__ A, const unsigned short* __restrict__ B,
             const float* __restrict__ bias, float* __restrict__ C,
             int N, int K,
             const int* __restrict__ cnts, const int* __restrict__ offs,
             const float* __restrict__ rowscale,
             long strideBe, int strideBiasE) {
  __shared__ __align__(16) unsigned short lds[2][2][128][32];
  const int gxd = gridDim.x;
  const int nwg = gxd * gridDim.y;
  const int wg = xcd_swizzle(blockIdx.y * gxd + blockIdx.x, nwg);
  const int mb = wg % gxd, nb = wg / gxd;

  int mcnt = 1 << 30;
  const float* rs = rowscale;
  if (ROUTED) {
    const int e = blockIdx.z;
    mcnt = cnts[e];
    if (mb * 128 >= mcnt) return;
    const long off = offs[e];
    A += off * (long)K;
    B += (long)e * strideBe;
    bias += (long)e * strideBiasE;
    C += off * (long)N;
    if (MODE == 2) rs = rowscale + off;
  }
  const int t = threadIdx.x;
  f32x4 acc[4][4] = {};
  const int nk = K >> 5;

  auto stage = [&](int kt, int buf) {
    #pragma unroll
    for (int i = 0; i < 2; ++i) {
      const int row = i * 64 + (t >> 2);
      const int ch = (t & 3) * 8;
      const unsigned short* ga = A + (long)(mb * 128 + row) * K + kt * 32 + ch;
      const unsigned short* gb = B + (long)(nb * 128 + row) * K + kt * 32 + ch;
      unsigned short* la = &lds[buf][0][0][0] + i * 2048 + t * 8;
      unsigned short* lb = &lds[buf][1][0][0] + i * 2048 + t * 8;
      __builtin_amdgcn_global_load_lds((const __attribute__((address_space(1))) unsigned int*)ga,
                                       (__attribute__((address_space(3))) unsigned int*)la, 16, 0, 0);
      __builtin_amdgcn_global_load_lds((const __attribute__((address_space(1))) unsigned int*)gb,
                                       (__attribute__((address_space(3))) unsigned int*)lb, 16, 0, 0);
    }
  };

  const int l = t & 63;
  const int w = t >> 6;
  const int wr = (w >> 1) * 64, wc = (w & 1) * 64;
  const int lr = l & 15, lk = (l >> 4) * 8;

  auto compute = [&](int buf) {
    bf16x8 a[4], b[4];
    #pragma unroll
    for (int m = 0; m < 4; ++m) a[m] = *(const bf16x8*)&lds[buf][0][wr + m * 16 + lr][lk];
    #pragma unroll
    for (int n = 0; n < 4; ++n) b[n] = *(const bf16x8*)&lds[buf][1][wc + n * 16 + lr][lk];
    #pragma unroll
    for (int m = 0; m < 4; ++m)
      #pragma unroll
      for (int n = 0; n < 4; ++n)
        acc[m][n] = __builtin_amdgcn_mfma_f32_16x16x32_bf16(a[m], b[n], acc[m][n], 0, 0, 0);
  };

  stage(0, 0);
  asm volatile("s_waitcnt vmcnt(0)" ::: "memory");
  __syncthreads();
  for (int kt = 0; kt < nk - 1; ++kt) {
    const int cur = kt & 1;
    stage(kt + 1, cur ^ 1);
    compute(cur);
    asm volatile("s_waitcnt vmcnt(0)" ::: "memory");
    __syncthreads();
  }
  compute((nk - 1) & 1);

  #pragma unroll
  for (int m = 0; m < 4; ++m) {
    #pragma unroll
    for (int n = 0; n < 4; ++n) {
      const int col = nb * 128 + wc + n * 16 + lr;
      const float bc = bias[col];
      #pragma unroll
      for (int j = 0; j < 4; ++j) {
        const int lrow = mb * 128 + wr + m * 16 + (l >> 4) * 4 + j;
        if (ROUTED && lrow >= mcnt) continue;
        float v = acc[m][n][j] + bc;
        if (MODE == 1) C[(long)lrow * N + col] = v;
        else           C[(long)lrow * N + col] = v * rs[lrow];
      }
    }
  }
}

// ---------------------------------------------------------------- host

extern "C" void kernel_launch(void* const* d_in, const int* in_sizes, int n_in,
                              void* d_out, int out_size, void* d_ws, size_t ws_size,
                              hipStream_t stream) {
  const float* x   = (const float*)d_in[0];
  const float* gw  = (const float*)d_in[1];
  const float* gb  = (const float*)d_in[2];
  const float* rb  = (const float*)d_in[3];
  const float* sw1 = (const float*)d_in[4];
  const float* sb1 = (const float*)d_in[5];
  const float* sw2 = (const float*)d_in[6];
  const float* sb2 = (const float*)d_in[7];
  const float* ew1 = (const float*)d_in[8];
  const float* eb1 = (const float*)d_in[9];
  const float* ew2 = (const float*)d_in[10];
  const float* eb2 = (const float*)d_in[11];

  char* wsp = (char*)d_ws;
  size_t o = 0;
  auto alloc = [&](size_t b) -> void* {
    void* p = wsp + o;
    o = (o + b + 255) & ~(size_t)255;
    return p;
  };
  unsigned short* x_bf = (unsigned short*)alloc((size_t)T_TOK * H_DIM * 2);
  unsigned short* w1s  = (unsigned short*)alloc((size_t)F_DIM * H_DIM * 2);
  unsigned short* w2s  = (unsigned short*)alloc((size_t)H_DIM * F_DIM * 2);
  unsigned short* w1e  = (unsigned short*)alloc((size_t)NEXP * F_DIM * H_DIM * 2);
  unsigned short* w2e  = (unsigned short*)alloc((size_t)NEXP * H_DIM * F_DIM * 2);
  unsigned short* gx   = (unsigned short*)alloc((size_t)(RT + RPAD) * H_DIM * 2);
  unsigned short* hs   = (unsigned short*)alloc((size_t)T_TOK * F_DIM * 2);        // shared h
  unsigned short* hr   = (unsigned short*)alloc((size_t)(RT + RPAD) * F_DIM * 2);  // routed h
  float* rout          = (float*)alloc((size_t)RT * H_DIM * 4);
  int*   tok_e  = (int*)alloc(2 * T_TOK * 4);
  float* tok_w  = (float*)alloc(2 * T_TOK * 4);
  int*   tokpos = (int*)alloc(2 * T_TOK * 4);
  int*   btok   = (int*)alloc(RT * 4);
  float* bw     = (float*)alloc(RT * 4);
  int*   meta   = (int*)alloc(1024);
  int* counts = meta, *cursor = meta + 8, *offs = meta + 16;
  (void)ws_size; (void)in_sizes; (void)n_in; (void)out_size;

  float* out = (float*)d_out;

  zero_kernel<<<1, 64, 0, stream>>>(meta);
  convert_kernel<<<2048, 256, 0, stream>>>(x,   x_bf, T_TOK * H_DIM / 8);
  convert_kernel<<<2048, 256, 0, stream>>>(sw1, w1s, F_DIM * H_DIM / 8);
  convert_kernel<<<2048, 256, 0, stream>>>(sw2, w2s, H_DIM * F_DIM / 8);
  convert_kernel<<<2048, 256, 0, stream>>>(ew1, w1e, NEXP * F_DIM * H_DIM / 8);
  convert_kernel<<<2048, 256, 0, stream>>>(ew2, w2e, NEXP * H_DIM * F_DIM / 8);
  gate_kernel<<<T_TOK, 64, 0, stream>>>(x, gw, gb, rb, tok_e, tok_w, counts);
  scan_kernel<<<1, 1, 0, stream>>>(counts, offs);
  build_kernel<<<T_TOK / 256, 256, 0, stream>>>(tok_e, tok_w, offs, cursor, btok, bw, tokpos);
  gather_kernel<<<RT, 128, 0, stream>>>(x, btok, gx);

  // GEMM1s: 256^2 tile, K=1024
  gemm256<false><<<dim3(T_TOK / 256, F_DIM / 256), 512, 0, stream>>>(
      x_bf, w1s, sb1, hs, F_DIM, H_DIM, nullptr, nullptr, 0, 0);
  gemm256<true><<<dim3(RT / 256, F_DIM / 256, NEXP), 512, 0, stream>>>(
      gx, w1e, eb1, hr, F_DIM, H_DIM, counts, offs,
      (long)F_DIM * H_DIM, F_DIM);

  // GEMM2s: 128^2 tile, K=4096
  gemm_nt<1, false><<<dim3(T_TOK / 128, H_DIM / 128), 256, 0, stream>>>(
      hs, w2s, sb2, out, H_DIM, F_DIM, nullptr, nullptr, nullptr, 0, 0);
  gemm_nt<2, true><<<dim3(RT / 128, H_DIM / 128, NEXP), 256, 0, stream>>>(
      hr, w2e, eb2, rout, H_DIM, F_DIM, counts, offs, bw,
      (long)H_DIM * F_DIM, H_DIM);

  combine_kernel<<<T_TOK, 256, 0, stream>>>(out, rout, tokpos);
}

// Round 3
// 710.370 us; speedup vs baseline: 1.6721x; 1.0924x over previous
//
#include <hip/hip_runtime.h>
#include <hip/hip_bf16.h>
#include <math.h>

// DeepSeekMoE: T=4096 tokens, H=1024, F=4096, E=8, top-2 sigmoid routing.
// Round 3: 9-group grouped GEMMs (shared FFN = group 8) to fix grid starvation
// (GEMM2 was 1 block/CU). x->bf16 fused into gate kernel.

#define T_TOK 4096
#define H_DIM 1024
#define F_DIM 4096
#define NEXP  8
#define RT    (2 * T_TOK)   // total routed rows (always exactly 2T)
#define RPAD  512           // padding rows for 256-tile tail reads

typedef __bf16 bf16_t;
typedef __bf16 bf16x8 __attribute__((ext_vector_type(8)));
typedef float  f32x4  __attribute__((ext_vector_type(4)));
typedef unsigned short u16x8 __attribute__((ext_vector_type(8)));

__device__ __forceinline__ unsigned short f2bf(float f) {
  union { bf16_t b; unsigned short u; } cv;
  cv.b = (bf16_t)f;   // fptrunc float->bfloat is RNE
  return cv.u;
}

__device__ __forceinline__ float gelu_exact(float v) {
  return 0.5f * v * (1.0f + erff(v * 0.70710678118654752f));
}

// bijective XCD swizzle (m204): contiguous wg chunk per XCD
__device__ __forceinline__ int xcd_swizzle(int orig, int nwg) {
  const int q = nwg >> 3, r = nwg & 7;
  const int xcd = orig & 7, idx = orig >> 3;
  return (xcd < r ? xcd * (q + 1) : r * (q + 1) + (xcd - r) * q) + idx;
}

// ---------------------------------------------------------------- small kernels

__global__ void zero_kernel(int* p) {
  if (threadIdx.x < 16) p[threadIdx.x] = 0;   // counts[8] + cursor[8]
}

__global__ void convert_kernel(const float* __restrict__ src,
                               unsigned short* __restrict__ dst, int n8) {
  int i = blockIdx.x * blockDim.x + threadIdx.x;
  int stride = gridDim.x * blockDim.x;
  for (; i < n8; i += stride) {
    const f32x4* s = (const f32x4*)src + (long)i * 2;
    f32x4 v0 = s[0], v1 = s[1];
    u16x8 o;
    #pragma unroll
    for (int j = 0; j < 4; ++j) { o[j] = f2bf(v0[j]); o[4 + j] = f2bf(v1[j]); }
    *(u16x8*)(dst + (long)i * 8) = o;
  }
}

// one wave per token: 8 gate scores -> sigmoid -> top2; also emits x in bf16
__global__ void gate_kernel(const float* __restrict__ x, const float* __restrict__ gw,
                            const float* __restrict__ gb, const float* __restrict__ rb,
                            unsigned short* __restrict__ x_bf,
                            int* __restrict__ tok_e, float* __restrict__ tok_w,
                            int* __restrict__ counts) {
  int tkn = blockIdx.x;
  int lane = threadIdx.x;
  float acc[NEXP];
  #pragma unroll
  for (int e = 0; e < NEXP; ++e) acc[e] = 0.f;
  const float* xr = x + (long)tkn * H_DIM;
  unsigned short* xbr = x_bf + (long)tkn * H_DIM;
  for (int k = lane; k < H_DIM; k += 64) {
    float xv = xr[k];
    xbr[k] = f2bf(xv);
    #pragma unroll
    for (int e = 0; e < NEXP; ++e) acc[e] += xv * gw[e * H_DIM + k];
  }
  #pragma unroll
  for (int off = 32; off > 0; off >>= 1) {
    #pragma unroll
    for (int e = 0; e < NEXP; ++e) acc[e] += __shfl_xor(acc[e], off, 64);
  }
  if (lane == 0) {
    float s[NEXP];
    #pragma unroll
    for (int e = 0; e < NEXP; ++e)
      s[e] = 1.f / (1.f + expf(-(acc[e] + gb[e] + rb[e])));
    int e0 = 0;
    #pragma unroll
    for (int e = 1; e < NEXP; ++e) if (s[e] > s[e0]) e0 = e;     // first-occurrence ties
    int e1 = (e0 == 0) ? 1 : 0;
    #pragma unroll
    for (int e = 0; e < NEXP; ++e) if (e != e0 && e != e1 && s[e] > s[e1]) e1 = e;
    tok_e[2 * tkn] = e0;  tok_e[2 * tkn + 1] = e1;
    tok_w[2 * tkn] = s[e0]; tok_w[2 * tkn + 1] = s[e1];
    atomicAdd(&counts[e0], 1);
    atomicAdd(&counts[e1], 1);
  }
}

__global__ void scan_kernel(const int* __restrict__ counts, int* __restrict__ offs) {
  if (threadIdx.x == 0) {
    int o = 0;
    for (int e = 0; e < NEXP; ++e) { offs[e] = o; o += counts[e]; }
  }
}

__global__ void build_kernel(const int* __restrict__ tok_e, const float* __restrict__ tok_w,
                             const int* __restrict__ offs, int* __restrict__ cursor,
                             int* __restrict__ btok, float* __restrict__ bw,
                             int* __restrict__ tokpos) {
  int tkn = blockIdx.x * blockDim.x + threadIdx.x;
  if (tkn >= T_TOK) return;
  #pragma unroll
  for (int k = 0; k < 2; ++k) {
    int e = tok_e[2 * tkn + k];
    int p = offs[e] + atomicAdd(&cursor[e], 1);
    btok[p] = tkn;
    bw[p] = tok_w[2 * tkn + k];
    tokpos[2 * tkn + k] = p;
  }
}

// copy x row (fp32) -> gathered bf16 row, bucket order
__global__ void gather_kernel(const float* __restrict__ x, const int* __restrict__ btok,
                              unsigned short* __restrict__ gx) {
  int p = blockIdx.x, tid = threadIdx.x;  // 128 threads * 8 elems
  int tkn = btok[p];
  const f32x4* s = (const f32x4*)(x + (long)tkn * H_DIM);
  f32x4 v0 = s[tid * 2], v1 = s[tid * 2 + 1];
  u16x8 o;
  #pragma unroll
  for (int j = 0; j < 4; ++j) { o[j] = f2bf(v0[j]); o[4 + j] = f2bf(v1[j]); }
  *(u16x8*)(gx + (long)p * H_DIM + tid * 8) = o;
}

__global__ void combine_kernel(float* __restrict__ out, const float* __restrict__ rout,
                               const int* __restrict__ tokpos) {
  int tkn = blockIdx.x, c = threadIdx.x;  // 256 threads * float4
  int p0 = tokpos[2 * tkn], p1 = tokpos[2 * tkn + 1];
  f32x4* o = (f32x4*)out + (long)tkn * 256;
  const f32x4* a = (const f32x4*)rout + (long)p0 * 256;
  const f32x4* b = (const f32x4*)rout + (long)p1 * 256;
  o[c] = o[c] + a[c] + b[c];
}

// ---------------------------------------------------------------- grouped GEMM1
// 256x256 tile, BK=32, 8 waves (2Mx4N), dbuf LDS 64KB, global_load_lds w16.
// C = gelu(A @ B^T + bias) in bf16. grid.z = group: 0..7 experts, 8 = shared.
// K = H_DIM = 1024, N = F_DIM = 4096.
__global__ __launch_bounds__(512)
void moe_gemm1(const unsigned short* __restrict__ x_bf, const unsigned short* __restrict__ gx,
               const unsigned short* __restrict__ w1s, const unsigned short* __restrict__ w1e,
               const float* __restrict__ sb1, const float* __restrict__ eb1,
               unsigned short* __restrict__ hbuf,
               const int* __restrict__ cnts, const int* __restrict__ offs) {
  __shared__ __align__(16) unsigned short lds[2][2][256][32];   // 64 KB
  const int gxd = gridDim.x;
  const int nwg = gxd * gridDim.y;
  const int wg = xcd_swizzle(blockIdx.y * gxd + blockIdx.x, nwg);
  const int mb = wg % gxd, nb = wg / gxd;

  const int z = blockIdx.z;
  const unsigned short* A;
  const unsigned short* Bp;
  const float* bias;
  unsigned short* C;
  int mcnt;
  if (z == NEXP) {
    A = x_bf; Bp = w1s; bias = sb1; C = hbuf; mcnt = T_TOK;
  } else {
    const int off = offs[z];
    mcnt = cnts[z];
    A = gx + (long)off * H_DIM;
    Bp = w1e + (long)z * F_DIM * H_DIM;
    bias = eb1 + z * F_DIM;
    C = hbuf + ((long)T_TOK + off) * F_DIM;
  }
  if (mb * 256 >= mcnt) return;

  const int t = threadIdx.x;
  f32x4 acc[8][4] = {};
  const int nk = H_DIM >> 5;   // 32 K-steps

  auto stage = [&](int kt, int buf) {
    #pragma unroll
    for (int i = 0; i < 2; ++i) {
      const int row = i * 128 + (t >> 2);
      const int ch = (t & 3) * 8;
      const unsigned short* ga = A + (long)(mb * 256 + row) * H_DIM + kt * 32 + ch;
      const unsigned short* gb = Bp + (long)(nb * 256 + row) * H_DIM + kt * 32 + ch;
      unsigned short* la = &lds[buf][0][0][0] + i * 4096 + t * 8;
      unsigned short* lb = &lds[buf][1][0][0] + i * 4096 + t * 8;
      __builtin_amdgcn_global_load_lds((const __attribute__((address_space(1))) unsigned int*)ga,
                                       (__attribute__((address_space(3))) unsigned int*)la, 16, 0, 0);
      __builtin_amdgcn_global_load_lds((const __attribute__((address_space(1))) unsigned int*)gb,
                                       (__attribute__((address_space(3))) unsigned int*)lb, 16, 0, 0);
    }
  };

  const int l = t & 63;
  const int w = t >> 6;                       // 8 waves: 2M x 4N
  const int wr = (w >> 2) * 128, wc = (w & 3) * 64;
  const int lr = l & 15, lk = (l >> 4) * 8;

  auto compute = [&](int buf) {
    bf16x8 a[8], b[4];
    #pragma unroll
    for (int m = 0; m < 8; ++m) a[m] = *(const bf16x8*)&lds[buf][0][wr + m * 16 + lr][lk];
    #pragma unroll
    for (int n = 0; n < 4; ++n) b[n] = *(const bf16x8*)&lds[buf][1][wc + n * 16 + lr][lk];
    #pragma unroll
    for (int m = 0; m < 8; ++m)
      #pragma unroll
      for (int n = 0; n < 4; ++n)
        acc[m][n] = __builtin_amdgcn_mfma_f32_16x16x32_bf16(a[m], b[n], acc[m][n], 0, 0, 0);
  };

  stage(0, 0);
  asm volatile("s_waitcnt vmcnt(0)" ::: "memory");
  __syncthreads();
  for (int kt = 0; kt < nk - 1; ++kt) {
    const int cur = kt & 1;
    stage(kt + 1, cur ^ 1);
    compute(cur);
    asm volatile("s_waitcnt vmcnt(0)" ::: "memory");
    __syncthreads();
  }
  compute((nk - 1) & 1);

  // epilogue: C/D layout col=lane&15, row=(lane>>4)*4+j (m89-verified)
  #pragma unroll
  for (int m = 0; m < 8; ++m) {
    #pragma unroll
    for (int n = 0; n < 4; ++n) {
      const int col = nb * 256 + wc + n * 16 + lr;
      const float bc = bias[col];
      #pragma unroll
      for (int j = 0; j < 4; ++j) {
        const int lrow = mb * 256 + wr + m * 16 + (l >> 4) * 4 + j;
        if (lrow >= mcnt) continue;   // expert tail rows belong to next group
        float v = acc[m][n][j] + bc;
        C[(long)lrow * F_DIM + col] = f2bf(gelu_exact(v));
      }
    }
  }
}

// ---------------------------------------------------------------- grouped GEMM2
// 128x128 tile, BK=32, 4 waves. C = (A @ B^T + bias) [* rowscale] in f32.
// grid.z = group: 0..7 experts (rowscale=bw, C=rout), 8 = shared (C=out).
// K = F_DIM = 4096, N = H_DIM = 1024.
__global__ __launch_bounds__(256)
void moe_gemm2(const unsigned short* __restrict__ hbuf,
               const unsigned short* __restrict__ w2s, const unsigned short* __restrict__ w2e,
               const float* __restrict__ sb2, const float* __restrict__ eb2,
               float* __restrict__ out, float* __restrict__ rout,
               const float* __restrict__ bw,
               const int* __restrict__ cnts, const int* __restrict__ offs) {
  __shared__ __align__(16) unsigned short lds[2][2][128][32];
  const int gxd = gridDim.x;
  const int nwg = gxd * gridDim.y;
  const int wg = xcd_swizzle(blockIdx.y * gxd + blockIdx.x, nwg);
  const int mb = wg % gxd, nb = wg / gxd;

  const int z = blockIdx.z;
  const unsigned short* A;
  const unsigned short* Bp;
  const float* bias;
  float* C;
  const float* rs;
  int mcnt;
  if (z == NEXP) {
    A = hbuf; Bp = w2s; bias = sb2; C = out; rs = nullptr; mcnt = T_TOK;
  } else {
    const int off = offs[z];
    mcnt = cnts[z];
    A = hbuf + ((long)T_TOK + off) * F_DIM;
    Bp = w2e + (long)z * H_DIM * F_DIM;
    bias = eb2 + z * H_DIM;
    C = rout + (long)off * H_DIM;
    rs = bw + off;
  }
  if (mb * 128 >= mcnt) return;

  const int t = threadIdx.x;
  f32x4 acc[4][4] = {};
  const int nk = F_DIM >> 5;   // 128 K-steps

  auto stage = [&](int kt, int buf) {
    #pragma unroll
    for (int i = 0; i < 2; ++i) {
      const int row = i * 64 + (t >> 2);
      const int ch = (t & 3) * 8;
      const unsigned short* ga = A + (long)(mb * 128 + row) * F_DIM + kt * 32 + ch;
      const unsigned short* gb = Bp + (long)(nb * 128 + row) * F_DIM + kt * 32 + ch;
      unsigned short* la = &lds[buf][0][0][0] + i * 2048 + t * 8;
      unsigned short* lb = &lds[buf][1][0][0] + i * 2048 + t * 8;
      __builtin_amdgcn_global_load_lds((const __attribute__((address_space(1))) unsigned int*)ga,
                                       (__attribute__((address_space(3))) unsigned int*)la, 16, 0, 0);
      __builtin_amdgcn_global_load_lds((const __attribute__((address_space(1))) unsigned int*)gb,
                                       (__attribute__((address_space(3))) unsigned int*)lb, 16, 0, 0);
    }
  };

  const int l = t & 63;
  const int w = t >> 6;
  const int wr = (w >> 1) * 64, wc = (w & 1) * 64;
  const int lr = l & 15, lk = (l >> 4) * 8;

  auto compute = [&](int buf) {
    bf16x8 a[4], b[4];
    #pragma unroll
    for (int m = 0; m < 4; ++m) a[m] = *(const bf16x8*)&lds[buf][0][wr + m * 16 + lr][lk];
    #pragma unroll
    for (int n = 0; n < 4; ++n) b[n] = *(const bf16x8*)&lds[buf][1][wc + n * 16 + lr][lk];
    #pragma unroll
    for (int m = 0; m < 4; ++m)
      #pragma unroll
      for (int n = 0; n < 4; ++n)
        acc[m][n] = __builtin_amdgcn_mfma_f32_16x16x32_bf16(a[m], b[n], acc[m][n], 0, 0, 0);
  };

  stage(0, 0);
  asm volatile("s_waitcnt vmcnt(0)" ::: "memory");
  __syncthreads();
  for (int kt = 0; kt < nk - 1; ++kt) {
    const int cur = kt & 1;
    stage(kt + 1, cur ^ 1);
    compute(cur);
    asm volatile("s_waitcnt vmcnt(0)" ::: "memory");
    __syncthreads();
  }
  compute((nk - 1) & 1);

  const bool has_rs = (z != NEXP);
  #pragma unroll
  for (int m = 0; m < 4; ++m) {
    #pragma unroll
    for (int n = 0; n < 4; ++n) {
      const int col = nb * 128 + wc + n * 16 + lr;
      const float bc = bias[col];
      #pragma unroll
      for (int j = 0; j < 4; ++j) {
        const int lrow = mb * 128 + wr + m * 16 + (l >> 4) * 4 + j;
        if (lrow >= mcnt) continue;
        float v = acc[m][n][j] + bc;
        if (has_rs) v *= rs[lrow];
        C[(long)lrow * H_DIM + col] = v;
      }
    }
  }
}

// ---------------------------------------------------------------- host

extern "C" void kernel_launch(void* const* d_in, const int* in_sizes, int n_in,
                              void* d_out, int out_size, void* d_ws, size_t ws_size,
                              hipStream_t stream) {
  const float* x   = (const float*)d_in[0];
  const float* gw  = (const float*)d_in[1];
  const float* gb  = (const float*)d_in[2];
  const float* rb  = (const float*)d_in[3];
  const float* sw1 = (const float*)d_in[4];
  const float* sb1 = (const float*)d_in[5];
  const float* sw2 = (const float*)d_in[6];
  const float* sb2 = (const float*)d_in[7];
  const float* ew1 = (const float*)d_in[8];
  const float* eb1 = (const float*)d_in[9];
  const float* ew2 = (const float*)d_in[10];
  const float* eb2 = (const float*)d_in[11];

  char* wsp = (char*)d_ws;
  size_t o = 0;
  auto alloc = [&](size_t b) -> void* {
    void* p = wsp + o;
    o = (o + b + 255) & ~(size_t)255;
    return p;
  };
  unsigned short* x_bf = (unsigned short*)alloc((size_t)T_TOK * H_DIM * 2);
  unsigned short* w1s  = (unsigned short*)alloc((size_t)F_DIM * H_DIM * 2);
  unsigned short* w2s  = (unsigned short*)alloc((size_t)H_DIM * F_DIM * 2);
  unsigned short* w1e  = (unsigned short*)alloc((size_t)NEXP * F_DIM * H_DIM * 2);
  unsigned short* w2e  = (unsigned short*)alloc((size_t)NEXP * H_DIM * F_DIM * 2);
  unsigned short* gx   = (unsigned short*)alloc((size_t)(RT + RPAD) * H_DIM * 2);
  unsigned short* hbuf = (unsigned short*)alloc((size_t)(T_TOK + RT + RPAD) * F_DIM * 2);
  float* rout          = (float*)alloc((size_t)RT * H_DIM * 4);
  int*   tok_e  = (int*)alloc(2 * T_TOK * 4);
  float* tok_w  = (float*)alloc(2 * T_TOK * 4);
  int*   tokpos = (int*)alloc(2 * T_TOK * 4);
  int*   btok   = (int*)alloc(RT * 4);
  float* bw     = (float*)alloc(RT * 4);
  int*   meta   = (int*)alloc(1024);
  int* counts = meta, *cursor = meta + 8, *offs = meta + 16;
  (void)ws_size; (void)in_sizes; (void)n_in; (void)out_size;

  float* out = (float*)d_out;

  zero_kernel<<<1, 64, 0, stream>>>(meta);
  convert_kernel<<<2048, 256, 0, stream>>>(sw1, w1s, F_DIM * H_DIM / 8);
  convert_kernel<<<2048, 256, 0, stream>>>(sw2, w2s, H_DIM * F_DIM / 8);
  convert_kernel<<<2048, 256, 0, stream>>>(ew1, w1e, NEXP * F_DIM * H_DIM / 8);
  convert_kernel<<<2048, 256, 0, stream>>>(ew2, w2e, NEXP * H_DIM * F_DIM / 8);
  gate_kernel<<<T_TOK, 64, 0, stream>>>(x, gw, gb, rb, x_bf, tok_e, tok_w, counts);
  scan_kernel<<<1, 1, 0, stream>>>(counts, offs);
  build_kernel<<<T_TOK / 256, 256, 0, stream>>>(tok_e, tok_w, offs, cursor, btok, bw, tokpos);
  gather_kernel<<<RT, 128, 0, stream>>>(x, btok, gx);

  // grouped GEMM1: groups 0-7 = experts, 8 = shared. K=1024, N=4096.
  moe_gemm1<<<dim3(T_TOK / 256, F_DIM / 256, NEXP + 1), 512, 0, stream>>>(
      x_bf, gx, w1s, w1e, sb1, eb1, hbuf, counts, offs);

  // grouped GEMM2: K=4096, N=1024.
  moe_gemm2<<<dim3(T_TOK / 128, H_DIM / 128, NEXP + 1), 256, 0, stream>>>(
      hbuf, w2s, w2e, sb2, eb2, out, rout, bw, counts, offs);

  combine_kernel<<<T_TOK, 256, 0, stream>>>(out, rout, tokpos);
}